// Round 8
// baseline (83.658 us; speedup 1.0000x reference)
//
#include <hip/hip_runtime.h>
#include <hip/hip_bf16.h>

#define S_DIM 2048
#define G_DIM 8
#define D_DIM 128
#define N_ROWS (S_DIM * G_DIM)   // 16384
#define SCALE 30.0f
#define NSPLIT 8
#define TCHUNK (S_DIM / NSPLIT)  // 256 speakers per block -> 64 KB LDS tile
#define NCOMBINE 64

typedef __attribute__((ext_vector_type(8))) short bf16x8;
typedef __attribute__((ext_vector_type(4))) float f32x4;

__device__ __forceinline__ float wave_allreduce_sum(float v) {
    #pragma unroll
    for (int m = 32; m >= 1; m >>= 1) v += __shfl_xor(v, m, 64);
    return v;
}

// ---------------------------------------------------------------------------
// Kernel A: normalize rows -> bf16 xn (materialized once; R4: in-score
// normalization re-pays fp32 reads x NSPLIT, +9us), bf16 normalized
// centroids, fp32 exclusive-centroid cosine. Block 0 zeroes the final
// accumulator + completion counter (stream-ordered before combine).
// ---------------------------------------------------------------------------
__global__ __launch_bounds__(512) void prep_kernel(
    const float* __restrict__ x,          // [S][G][D]
    __hip_bfloat16* __restrict__ xnb,     // [S*G][D]
    __hip_bfloat16* __restrict__ centb,   // [S][D]
    float* __restrict__ cosexc,           // [S*G]
    float* __restrict__ acc_out,          // [1]
    unsigned int* __restrict__ counter)   // [1]
{
    __shared__ float xs[G_DIM][D_DIM];
    __shared__ float csum[D_DIM];

    const int s    = blockIdx.x;
    const int g    = threadIdx.x >> 6;
    const int lane = threadIdx.x & 63;
    const int d0 = lane, d1 = lane + 64;

    if (s == 0 && threadIdx.x == 0) { acc_out[0] = 0.0f; counter[0] = 0u; }

    const float* xr = x + (s * G_DIM + g) * D_DIM;
    float a0 = xr[d0], a1 = xr[d1];

    float ss  = wave_allreduce_sum(a0 * a0 + a1 * a1);
    float inv = 1.0f / fmaxf(sqrtf(ss), 1e-12f);
    float x0 = a0 * inv, x1 = a1 * inv;

    xs[g][d0] = x0;
    xs[g][d1] = x1;
    __hip_bfloat16* xw = xnb + (s * G_DIM + g) * D_DIM;
    xw[d0] = __float2bfloat16(x0);
    xw[d1] = __float2bfloat16(x1);
    __syncthreads();

    if (threadIdx.x < D_DIM) {
        float c = 0.0f;
        #pragma unroll
        for (int gg = 0; gg < G_DIM; ++gg) c += xs[gg][threadIdx.x];
        csum[threadIdx.x] = c;
    }
    __syncthreads();

    float e0 = (csum[d0] - x0) * (1.0f / (G_DIM - 1));
    float e1 = (csum[d1] - x1) * (1.0f / (G_DIM - 1));
    float ess = wave_allreduce_sum(e0 * e0 + e1 * e1);
    float ed  = fmaxf(sqrtf(ess), 1e-8f);
    float dot = wave_allreduce_sum(x0 * e0 + x1 * e1);
    if (lane == 0) cosexc[s * G_DIM + g] = dot / ed;

    if (g == 0) {
        float c0 = csum[d0], c1 = csum[d1];
        float css  = wave_allreduce_sum(c0 * c0 + c1 * c1);
        float cnrm = sqrtf(css) * (1.0f / G_DIM);
        float scl  = (1.0f / G_DIM) / fmaxf(cnrm, 1e-8f);
        centb[s * D_DIM + d0] = __float2bfloat16(c0 * scl);
        centb[s * D_DIM + d1] = __float2bfloat16(c1 * scl);
    }
}

// ---------------------------------------------------------------------------
// Kernel B: fused scores + softmax-denominator.
// R7->R8: score's time tracks global/L2-path traffic volume (R2: 512MB->66us,
// R3: 128MB->29us, R7: 96MB->~18us; effective BW only ~5-8 TB/s on the
// cross-XCD/post-poison path). A-reads = NSPLIT x 4MB dominate now, so
// NSPLIT 16->8: TCHUNK=256 -> 64 KB LDS B-tile, 512 blocks = 2/CU
// (LDS-bound), 16 t-iters/wave. Global traffic 96 -> 64 MB.
// Occupancy 8 waves/CU — acceptable since in-loop global latency is gone
// (LDS-fed loop).
// Staging: global_load_lds width=16, source-permuted: LDS slot (r, cc)
// holds global chunk (cc - r) & 15; readers fetch cc = (quad+4kc+lr) & 15
// -> per-16-lane phase each 4-bank group hit exactly 2x = free [m136].
// A-frag (16x16x32): A[m=lane&15][k=(lane>>4)*8+j]. C/D: col=lane&15,
// row=(lane>>4)*4+reg [m89-verified]. Diagonal band hits exactly one 16-t
// tile -> wave-uniform branch; plab written once by the owning split.
// logsumexp offset fixed at 30 (logits in (0,30]): no max pass.
// ---------------------------------------------------------------------------
__global__ __launch_bounds__(256, 2) void score_kernel(
    const __hip_bfloat16* __restrict__ xnb,    // [N_ROWS][D]
    const __hip_bfloat16* __restrict__ centb,  // [S][D]
    const float* __restrict__ cosexc,          // [N_ROWS]
    float* __restrict__ psum,                  // [NSPLIT][N_ROWS]
    float* __restrict__ plab)                  // [N_ROWS]
{
    __shared__ short bsm[TCHUNK * D_DIM];      // 64 KB, source-permuted

    const int wave  = threadIdx.x >> 6;
    const int lane  = threadIdx.x & 63;
    const int tid   = threadIdx.x;
    const int row0  = (blockIdx.x * 4 + wave) * 64;   // 64 rows per wave
    const int split = blockIdx.y;
    const int tbase = split * TCHUNK;
    const int nIdx  = lane & 15;
    const int quad  = lane >> 4;
    const int s0    = row0 >> 3;

    // ---- stage B tile into LDS (16B/lane x 16 slots/thread), permuted ----
    {
        const short* gsrc = (const short*)centb;
        #pragma unroll
        for (int j = 0; j < 16; ++j) {
            const int s  = j * 256 + tid;     // slot index (16B slots)
            const int r  = s >> 4;            // local speaker row 0..255
            const int cc = s & 15;            // LDS chunk column
            const int c  = (cc - r) & 15;     // global chunk held in this slot
            const short* g = gsrc + (size_t)(tbase + r) * D_DIM + c * 8;
            __builtin_amdgcn_global_load_lds(
                (const __attribute__((address_space(1))) void*)g,
                (__attribute__((address_space(3))) void*)
                    ((char*)bsm + j * 4096 + wave * 1024),
                16, 0, 0);
        }
    }

    // ---- A fragments resident: 4 tiles x 16 rows x 128 k ----
    const short* xsrc = (const short*)xnb;
    bf16x8 afrag[4][4];
    #pragma unroll
    for (int m = 0; m < 4; ++m) {
        const int abase = (row0 + m * 16 + nIdx) * D_DIM + quad * 8;
        #pragma unroll
        for (int kc = 0; kc < 4; ++kc)
            afrag[m][kc] = *(const bf16x8*)(xsrc + abase + kc * 32);
    }

    float sumexp[4][4];
    #pragma unroll
    for (int m = 0; m < 4; ++m)
        #pragma unroll
        for (int r = 0; r < 4; ++r) sumexp[m][r] = 0.0f;

    __syncthreads();   // staging complete (implicit vmcnt drain)

    for (int t0 = tbase; t0 < tbase + TCHUNK; t0 += 16) {
        const int lr = (t0 - tbase) + nIdx;    // local B row 0..255
        bf16x8 bfrag[4];
        #pragma unroll
        for (int kc = 0; kc < 4; ++kc) {
            const int cc = (quad + kc * 4 + lr) & 15;   // inverse rotation
            bfrag[kc] = *(const bf16x8*)(bsm + lr * D_DIM + cc * 8);
        }

        f32x4 acc[4];
        #pragma unroll
        for (int m = 0; m < 4; ++m) acc[m] = (f32x4){0.f, 0.f, 0.f, 0.f};
        #pragma unroll
        for (int kc = 0; kc < 4; ++kc)
            #pragma unroll
            for (int m = 0; m < 4; ++m)
                acc[m] = __builtin_amdgcn_mfma_f32_16x16x32_bf16(
                    afrag[m][kc], bfrag[kc], acc[m], 0, 0, 0);

        const int t = t0 + nIdx;
        if (t0 <= s0 + 7 && t0 + 16 > s0) {
            // rare tile containing this wave's diagonal band (wave-uniform)
            #pragma unroll
            for (int m = 0; m < 4; ++m) {
                #pragma unroll
                for (int r = 0; r < 4; ++r) {
                    const int grow = row0 + m * 16 + quad * 4 + r;
                    float l = fmaxf(SCALE * acc[m][r], 1e-6f);
                    if (t == (grow >> 3)) {
                        l = fmaxf(SCALE * cosexc[grow], 1e-6f);
                        plab[grow] = l;           // exactly one writer per row
                    }
                    sumexp[m][r] += __expf(l - SCALE);
                }
            }
        } else {
            #pragma unroll
            for (int m = 0; m < 4; ++m) {
                #pragma unroll
                for (int r = 0; r < 4; ++r) {
                    // exp(clamp(30a,1e-6)-30) == exp(max(30a-30, 1e-6-30))
                    float e = fmaxf(fmaf(SCALE, acc[m][r], -SCALE), 1e-6f - SCALE);
                    sumexp[m][r] += __expf(e);
                }
            }
        }
    }

    // reduce across the 16 lanes sharing a quad (they cover t mod 16)
    #pragma unroll
    for (int m = 0; m < 4; ++m) {
        #pragma unroll
        for (int r = 0; r < 4; ++r) {
            #pragma unroll
            for (int msk = 1; msk <= 8; msk <<= 1)
                sumexp[m][r] += __shfl_xor(sumexp[m][r], msk, 64);
        }
    }
    if (nIdx == 0) {
        #pragma unroll
        for (int m = 0; m < 4; ++m)
            #pragma unroll
            for (int r = 0; r < 4; ++r)
                psum[split * N_ROWS + row0 + m * 16 + quad * 4 + r] = sumexp[m][r];
    }
}

// ---------------------------------------------------------------------------
// Kernel C: combine partials -> per-row loss -> block sum -> device-scope
// atomic accumulate; LAST block writes the mean to d_out. [m20] atomics are
// device-scope; counter RMW + threadfence order the adds.
// ---------------------------------------------------------------------------
__global__ __launch_bounds__(256) void combine_kernel(
    const float* __restrict__ psum, const float* __restrict__ plab,
    float* __restrict__ acc_out, unsigned int* __restrict__ counter,
    float* __restrict__ out)
{
    __shared__ float red[4];
    const int row = blockIdx.x * 256 + threadIdx.x;

    float s = 0.0f;
    #pragma unroll
    for (int j = 0; j < NSPLIT; ++j) s += psum[j * N_ROWS + row];
    float loss = SCALE + logf(s) - plab[row];   // -logp[row, label]

    float v = wave_allreduce_sum(loss);
    const int wave = threadIdx.x >> 6;
    if ((threadIdx.x & 63) == 0) red[wave] = v;
    __syncthreads();
    if (threadIdx.x == 0) {
        atomicAdd(acc_out, red[0] + red[1] + red[2] + red[3]);
        __threadfence();
        unsigned int prev = atomicAdd(counter, 1u);
        if (prev == NCOMBINE - 1) {
            float total = atomicAdd(acc_out, 0.0f);   // coherent read
            out[0] = total * (1.0f / N_ROWS);
        }
    }
}

extern "C" void kernel_launch(void* const* d_in, const int* in_sizes, int n_in,
                              void* d_out, int out_size, void* d_ws, size_t ws_size,
                              hipStream_t stream) {
    const float* x = (const float*)d_in[0];
    char* ws = (char*)d_ws;

    size_t off = 0;
    __hip_bfloat16* xnb   = (__hip_bfloat16*)(ws + off); off += (size_t)N_ROWS * D_DIM * 2;  // 4 MB
    __hip_bfloat16* centb = (__hip_bfloat16*)(ws + off); off += (size_t)S_DIM * D_DIM * 2;   // 0.5 MB
    float* cosexc = (float*)(ws + off); off += (size_t)N_ROWS * 4;                            // 64 KB
    float* psum   = (float*)(ws + off); off += (size_t)NSPLIT * N_ROWS * 4;                   // 512 KB
    float* plab   = (float*)(ws + off); off += (size_t)N_ROWS * 4;                            // 64 KB
    float* acc    = (float*)(ws + off); off += 4;
    unsigned int* counter = (unsigned int*)(ws + off); off += 4;
    float* out = (float*)d_out;

    prep_kernel<<<S_DIM, 512, 0, stream>>>(x, xnb, centb, cosexc, acc, counter);
    score_kernel<<<dim3(N_ROWS / 256, NSPLIT), 256, 0, stream>>>(xnb, centb, cosexc, psum, plab);
    combine_kernel<<<NCOMBINE, 256, 0, stream>>>(psum, plab, acc, counter, out);
}

// Round 9
// 81.391 us; speedup vs baseline: 1.0279x; 1.0279x over previous
//
#include <hip/hip_runtime.h>
#include <hip/hip_bf16.h>

#define S_DIM 2048
#define G_DIM 8
#define D_DIM 128
#define N_ROWS (S_DIM * G_DIM)   // 16384
#define SCALE 30.0f
#define NSPLIT 16
#define TCHUNK (S_DIM / NSPLIT)  // 128 speakers per block -> 16 KB fp8 LDS tile
#define NCOMBINE 64

typedef __attribute__((ext_vector_type(4))) float f32x4;

__device__ __forceinline__ float wave_allreduce_sum(float v) {
    #pragma unroll
    for (int m = 32; m >= 1; m >>= 1) v += __shfl_xor(v, m, 64);
    return v;
}

// pack two floats -> two OCP e4m3 bytes (low 16 bits of result)
__device__ __forceinline__ unsigned short f2fp8x2(float a, float b) {
    int r = __builtin_amdgcn_cvt_pk_fp8_f32(a, b, 0, false);
    return (unsigned short)(r & 0xFFFF);
}

// ---------------------------------------------------------------------------
// Kernel A: normalize rows -> fp8 xn (2 MB; R9: fp8 halves score's A-traffic,
// which R2/R3/R7/R8 established as the governing quantity), fp8 normalized
// centroids, fp32 exclusive-centroid cosine (exact — label term must be
// precise). Lane handles ADJACENT dims 2*lane, 2*lane+1 so cvt_pk packs a
// 2-byte store. Byte order inside the pair is irrelevant: A and B use the
// same packing, and dot products are invariant under a shared k-permutation.
// Block 0 zeroes the final accumulator + completion counter.
// ---------------------------------------------------------------------------
__global__ __launch_bounds__(512) void prep_kernel(
    const float* __restrict__ x,              // [S][G][D]
    unsigned short* __restrict__ xnb8,        // [S*G][D/2] fp8 pairs
    unsigned short* __restrict__ centb8,      // [S][D/2]   fp8 pairs
    float* __restrict__ cosexc,               // [S*G]
    float* __restrict__ acc_out,              // [1]
    unsigned int* __restrict__ counter)       // [1]
{
    __shared__ float xs[G_DIM][D_DIM];
    __shared__ float csum[D_DIM];

    const int s    = blockIdx.x;
    const int g    = threadIdx.x >> 6;
    const int lane = threadIdx.x & 63;
    const int d0 = 2 * lane, d1 = 2 * lane + 1;

    if (s == 0 && threadIdx.x == 0) { acc_out[0] = 0.0f; counter[0] = 0u; }

    const float* xr = x + (s * G_DIM + g) * D_DIM;
    float a0 = xr[d0], a1 = xr[d1];

    float ss  = wave_allreduce_sum(a0 * a0 + a1 * a1);
    float inv = 1.0f / fmaxf(sqrtf(ss), 1e-12f);
    float x0 = a0 * inv, x1 = a1 * inv;

    xs[g][d0] = x0;
    xs[g][d1] = x1;
    xnb8[(s * G_DIM + g) * (D_DIM / 2) + lane] = f2fp8x2(x0, x1);
    __syncthreads();

    if (threadIdx.x < D_DIM) {
        float c = 0.0f;
        #pragma unroll
        for (int gg = 0; gg < G_DIM; ++gg) c += xs[gg][threadIdx.x];
        csum[threadIdx.x] = c;
    }
    __syncthreads();

    float e0 = (csum[d0] - x0) * (1.0f / (G_DIM - 1));
    float e1 = (csum[d1] - x1) * (1.0f / (G_DIM - 1));
    float ess = wave_allreduce_sum(e0 * e0 + e1 * e1);
    float ed  = fmaxf(sqrtf(ess), 1e-8f);
    float dot = wave_allreduce_sum(x0 * e0 + x1 * e1);
    if (lane == 0) cosexc[s * G_DIM + g] = dot / ed;

    if (g == 0) {
        float c0 = csum[d0], c1 = csum[d1];
        float css  = wave_allreduce_sum(c0 * c0 + c1 * c1);
        float cnrm = sqrtf(css) * (1.0f / G_DIM);
        float scl  = (1.0f / G_DIM) / fmaxf(cnrm, 1e-8f);
        centb8[s * (D_DIM / 2) + lane] = f2fp8x2(c0 * scl, c1 * scl);
    }
}

// ---------------------------------------------------------------------------
// Kernel B: fused scores + softmax-denominator, fp8 MFMA (fp32 acc; rate =
// bf16 rate [m11] but bytes halve — we are traffic-bound, not FLOP-bound).
// R7/R8 iso-line (96MB@4blk/CU == 64MB@2blk/CU) -> fp8 improves BOTH axes:
// 48 MB total traffic AND 16 KB LDS tile -> 1024 blocks at 4 blocks/CU.
// k-packing (A and B identical, so any HW k-permutation cancels): fragment
// i64 = bytes [kc*32 + quad*8, +8) of the 128-byte row.
// LDS staging via global_load_lds width=16, granule-rotated by row:
// LDS 16B-slot (r, cc) holds global granule (cc - r) & 7; readers use
// cc = (2kc + (quad>>1) + lr) & 7 -> banks ((g+r)&7)*4 + (quad&1)*2:
// 16 lanes spread over 8 bank-groups x2 = 2-way = free [m136].
// C/D: col=lane&15, row=(lane>>4)*4+reg (shape-determined, dtype-independent
// [m89/m121-128]). Diagonal band hits exactly one 16-t tile -> wave-uniform
// branch; label logit exact fp32 via cosexc. logsumexp offset fixed at 30.
// ---------------------------------------------------------------------------
__global__ __launch_bounds__(256, 4) void score_kernel(
    const unsigned char* __restrict__ xnb8,    // [N_ROWS][D] fp8
    const unsigned char* __restrict__ centb8,  // [S][D] fp8
    const float* __restrict__ cosexc,          // [N_ROWS]
    float* __restrict__ psum,                  // [NSPLIT][N_ROWS]
    float* __restrict__ plab)                  // [N_ROWS]
{
    __shared__ char bsm[TCHUNK * D_DIM];       // 16 KB, granule-rotated

    const int wave  = threadIdx.x >> 6;
    const int lane  = threadIdx.x & 63;
    const int tid   = threadIdx.x;
    const int row0  = (blockIdx.x * 4 + wave) * 64;   // 64 rows per wave
    const int split = blockIdx.y;
    const int tbase = split * TCHUNK;
    const int nIdx  = lane & 15;
    const int quad  = lane >> 4;
    const int s0    = row0 >> 3;

    // ---- stage B tile into LDS (16B granules, rotated by row) ----
    {
        #pragma unroll
        for (int j = 0; j < 4; ++j) {
            const int s  = j * 256 + tid;     // granule slot 0..1023
            const int r  = s >> 3;            // local speaker row 0..127
            const int cc = s & 7;             // LDS granule column
            const int c  = (cc - r) & 7;      // global granule held here
            const unsigned char* g = centb8 + (size_t)(tbase + r) * D_DIM + c * 16;
            __builtin_amdgcn_global_load_lds(
                (const __attribute__((address_space(1))) void*)g,
                (__attribute__((address_space(3))) void*)
                    ((char*)bsm + j * 4096 + wave * 1024),
                16, 0, 0);
        }
    }

    // ---- A fragments resident: 4 tiles x 16 rows, i64 per (m,kc) ----
    const long long* asrc = (const long long*)xnb8;   // 8-byte units
    long long afrag[4][4];
    #pragma unroll
    for (int m = 0; m < 4; ++m) {
        const int abase = (row0 + m * 16 + nIdx) * (D_DIM / 8);
        #pragma unroll
        for (int kc = 0; kc < 4; ++kc)
            afrag[m][kc] = asrc[abase + kc * 4 + quad];
    }

    float sumexp[4][4];
    #pragma unroll
    for (int m = 0; m < 4; ++m)
        #pragma unroll
        for (int r = 0; r < 4; ++r) sumexp[m][r] = 0.0f;

    __syncthreads();   // staging complete (implicit vmcnt drain)

    for (int t0 = tbase; t0 < tbase + TCHUNK; t0 += 16) {
        const int lr = (t0 - tbase) + nIdx;    // local B row 0..127
        long long bfrag[4];
        #pragma unroll
        for (int kc = 0; kc < 4; ++kc) {
            const int g  = 2 * kc + (quad >> 1);          // global granule
            const int cc = (g + lr) & 7;                  // rotated column
            bfrag[kc] = *(const long long*)
                (bsm + lr * D_DIM + cc * 16 + (quad & 1) * 8);
        }

        f32x4 acc[4];
        #pragma unroll
        for (int m = 0; m < 4; ++m) acc[m] = (f32x4){0.f, 0.f, 0.f, 0.f};
        #pragma unroll
        for (int kc = 0; kc < 4; ++kc)
            #pragma unroll
            for (int m = 0; m < 4; ++m)
                acc[m] = __builtin_amdgcn_mfma_f32_16x16x32_fp8_fp8(
                    afrag[m][kc], bfrag[kc], acc[m], 0, 0, 0);

        const int t = t0 + nIdx;
        if (t0 <= s0 + 7 && t0 + 16 > s0) {
            // rare tile containing this wave's diagonal band (wave-uniform)
            #pragma unroll
            for (int m = 0; m < 4; ++m) {
                #pragma unroll
                for (int r = 0; r < 4; ++r) {
                    const int grow = row0 + m * 16 + quad * 4 + r;
                    float l = fmaxf(SCALE * acc[m][r], 1e-6f);
                    if (t == (grow >> 3)) {
                        l = fmaxf(SCALE * cosexc[grow], 1e-6f);
                        plab[grow] = l;           // exactly one writer per row
                    }
                    sumexp[m][r] += __expf(l - SCALE);
                }
            }
        } else {
            #pragma unroll
            for (int m = 0; m < 4; ++m) {
                #pragma unroll
                for (int r = 0; r < 4; ++r) {
                    // exp(clamp(30a,1e-6)-30) == exp(max(30a-30, 1e-6-30))
                    float e = fmaxf(fmaf(SCALE, acc[m][r], -SCALE), 1e-6f - SCALE);
                    sumexp[m][r] += __expf(e);
                }
            }
        }
    }

    // reduce across the 16 lanes sharing a quad (they cover t mod 16)
    #pragma unroll
    for (int m = 0; m < 4; ++m) {
        #pragma unroll
        for (int r = 0; r < 4; ++r) {
            #pragma unroll
            for (int msk = 1; msk <= 8; msk <<= 1)
                sumexp[m][r] += __shfl_xor(sumexp[m][r], msk, 64);
        }
    }
    if (nIdx == 0) {
        #pragma unroll
        for (int m = 0; m < 4; ++m)
            #pragma unroll
            for (int r = 0; r < 4; ++r)
                psum[split * N_ROWS + row0 + m * 16 + quad * 4 + r] = sumexp[m][r];
    }
}

// ---------------------------------------------------------------------------
// Kernel C: combine partials -> per-row loss -> block sum -> device-scope
// atomic accumulate; LAST block writes the mean to d_out. [m20] atomics are
// device-scope; counter RMW + threadfence order the adds.
// ---------------------------------------------------------------------------
__global__ __launch_bounds__(256) void combine_kernel(
    const float* __restrict__ psum, const float* __restrict__ plab,
    float* __restrict__ acc_out, unsigned int* __restrict__ counter,
    float* __restrict__ out)
{
    __shared__ float red[4];
    const int row = blockIdx.x * 256 + threadIdx.x;

    float s = 0.0f;
    #pragma unroll
    for (int j = 0; j < NSPLIT; ++j) s += psum[j * N_ROWS + row];
    float loss = SCALE + logf(s) - plab[row];   // -logp[row, label]

    float v = wave_allreduce_sum(loss);
    const int wave = threadIdx.x >> 6;
    if ((threadIdx.x & 63) == 0) red[wave] = v;
    __syncthreads();
    if (threadIdx.x == 0) {
        atomicAdd(acc_out, red[0] + red[1] + red[2] + red[3]);
        __threadfence();
        unsigned int prev = atomicAdd(counter, 1u);
        if (prev == NCOMBINE - 1) {
            float total = atomicAdd(acc_out, 0.0f);   // coherent read
            out[0] = total * (1.0f / N_ROWS);
        }
    }
}

extern "C" void kernel_launch(void* const* d_in, const int* in_sizes, int n_in,
                              void* d_out, int out_size, void* d_ws, size_t ws_size,
                              hipStream_t stream) {
    const float* x = (const float*)d_in[0];
    char* ws = (char*)d_ws;

    size_t off = 0;
    unsigned short* xnb8   = (unsigned short*)(ws + off); off += (size_t)N_ROWS * D_DIM;  // 2 MB
    unsigned short* centb8 = (unsigned short*)(ws + off); off += (size_t)S_DIM * D_DIM;   // 256 KB
    float* cosexc = (float*)(ws + off); off += (size_t)N_ROWS * 4;                         // 64 KB
    float* psum   = (float*)(ws + off); off += (size_t)NSPLIT * N_ROWS * 4;                // 1 MB
    float* plab   = (float*)(ws + off); off += (size_t)N_ROWS * 4;                         // 64 KB
    float* acc    = (float*)(ws + off); off += 4;
    unsigned int* counter = (unsigned int*)(ws + off); off += 4;
    float* out = (float*)d_out;

    prep_kernel<<<S_DIM, 512, 0, stream>>>(x, xnb8, centb8, cosexc, acc, counter);
    score_kernel<<<dim3(N_ROWS / 256, NSPLIT), 256, 0, stream>>>(
        (const unsigned char*)xnb8, (const unsigned char*)centb8, cosexc, psum, plab);
    combine_kernel<<<NCOMBINE, 256, 0, stream>>>(psum, plab, acc, counter, out);
}